// Round 2
// baseline (589.680 us; speedup 1.0000x reference)
//
#include <hip/hip_runtime.h>
#include <math.h>

#define DIM 128
#define NEG_K 20

// Numerically stable log(sigmoid(x)) = min(x,0) - log1p(exp(-|x|))
__device__ __forceinline__ float log_sigmoid(float x) {
    float m = fminf(x, 0.0f);
    return m - log1pf(__expf(-fabsf(x)));
}

// One full wave per batch element; lane holds float4 (16B) so ONE
// global_load_dwordx4 moves 64*16B = 1024B = TWO embedding rows:
//   - neg rows: lower 32 lanes accumulate even-k rows, upper 32 odd-k rows
//     (10 gather instructions for 20 rows)
//   - v/u fused: lower half loads v-row, upper half loads u-row (1 instr)
// Cross-half combines are shfl_xor(.,32). Addresses are 32-bit byte offsets
// (row*512B < 2^31) so loads take the saddr + single-VGPR-voffset form.
__global__ __launch_bounds__(256) void sgns_partial_kernel(
    const int* __restrict__ target,
    const int* __restrict__ context,
    const int* __restrict__ neg,
    const float* __restrict__ emb,
    float* __restrict__ partials,
    int B)
{
    const int lane = threadIdx.x & 63;
    const unsigned sub  = lane & 31;   // column group: cols 4*sub .. 4*sub+3
    const int      half = lane >> 5;   // 0: even rows / v-row; 1: odd rows / u-row
    const int wid  = (blockIdx.x * blockDim.x + threadIdx.x) >> 6;
    const int nW   = (gridDim.x * blockDim.x) >> 6;

    const char* __restrict__ embB = (const char*)emb;

    float local = 0.0f;   // accumulated by lane 0 of each wave
    for (int b = wid; b < B; b += nW) {
        const int tgt = __builtin_amdgcn_readfirstlane(target[b]);
        const int ctx = __builtin_amdgcn_readfirstlane(context[b]);

        // 20 neg indices -> SGPRs (wave-uniform)
        const int4* __restrict__ nbv = (const int4*)(neg + (size_t)b * NEG_K);
        const int4 n0 = nbv[0], n1 = nbv[1], n2 = nbv[2], n3 = nbv[3], n4 = nbv[4];
        int ni[NEG_K] = { n0.x,n0.y,n0.z,n0.w, n1.x,n1.y,n1.z,n1.w,
                          n2.x,n2.y,n2.z,n2.w, n3.x,n3.y,n3.z,n3.w,
                          n4.x,n4.y,n4.z,n4.w };
        #pragma unroll
        for (int k = 0; k < NEG_K; ++k)
            ni[k] = __builtin_amdgcn_readfirstlane(ni[k]);

        // Fused v/u load: one wave instruction covers both rows.
        const int vuRow = half ? ctx : tgt;
        const unsigned vuOff = ((unsigned)vuRow << 9) | (sub << 4);  // row*512 + sub*16
        const float4 vu = *(const float4*)(embB + vuOff);

        // Accumulate neg rows, two per instruction.
        float4 ns = make_float4(0.f, 0.f, 0.f, 0.f);
        #pragma unroll
        for (int p = 0; p < NEG_K / 2; ++p) {
            const int row = half ? ni[2 * p + 1] : ni[2 * p];
            const unsigned off = ((unsigned)row << 9) | (sub << 4);
            const float4 un = *(const float4*)(embB + off);
            ns.x += un.x; ns.y += un.y; ns.z += un.z; ns.w += un.w;
        }
        // Combine even/odd halves of the neg row-sum (same columns, xor 32).
        ns.x += __shfl_xor(ns.x, 32);
        ns.y += __shfl_xor(ns.y, 32);
        ns.z += __shfl_xor(ns.z, 32);
        ns.w += __shfl_xor(ns.w, 32);

        // Swap halves of vu: lower lanes see u-frag, upper lanes see v-frag.
        float4 ot;
        ot.x = __shfl_xor(vu.x, 32);
        ot.y = __shfl_xor(vu.y, 32);
        ot.z = __shfl_xor(vu.z, 32);
        ot.w = __shfl_xor(vu.w, 32);

        // Per-lane partial dots. pos is valid in BOTH halves (v*u == u*v);
        // ng is valid in the lower half (ns * v-frag). Butterfly over 32
        // lanes keeps each half's reduction independent and complete.
        float pos = vu.x*ot.x + vu.y*ot.y + vu.z*ot.z + vu.w*ot.w;
        float ng  = ns.x*vu.x + ns.y*vu.y + ns.z*vu.z + ns.w*vu.w;
        #pragma unroll
        for (int off = 16; off; off >>= 1) {
            pos += __shfl_xor(pos, off);
            ng  += __shfl_xor(ng,  off);
        }
        if (lane == 0) local += log_sigmoid(pos) + log_sigmoid(-ng);
    }

    // One partial per block (no global atomics).
    __shared__ float wsum[4];
    if (lane == 0) wsum[threadIdx.x >> 6] = local;
    __syncthreads();
    if (threadIdx.x == 0)
        partials[blockIdx.x] = wsum[0] + wsum[1] + wsum[2] + wsum[3];
}

// Single-block reduction of the per-block partials; writes the final loss.
__global__ __launch_bounds__(256) void sgns_reduce_kernel(
    const float* __restrict__ partials, float* __restrict__ out,
    int n, float invB)
{
    float s = 0.0f;
    for (int i = threadIdx.x; i < n; i += 256) s += partials[i];
    #pragma unroll
    for (int off = 32; off; off >>= 1) s += __shfl_xor(s, off);

    __shared__ float wsum[4];
    const int lane = threadIdx.x & 63;
    if (lane == 0) wsum[threadIdx.x >> 6] = s;
    __syncthreads();
    if (threadIdx.x == 0)
        out[0] = -(wsum[0] + wsum[1] + wsum[2] + wsum[3]) * invB;
}

extern "C" void kernel_launch(void* const* d_in, const int* in_sizes, int n_in,
                              void* d_out, int out_size, void* d_ws, size_t ws_size,
                              hipStream_t stream) {
    const int*   target  = (const int*)d_in[0];
    const int*   context = (const int*)d_in[1];
    const int*   neg     = (const int*)d_in[2];
    const float* emb     = (const float*)d_in[3];
    float* out      = (float*)d_out;
    float* partials = (float*)d_ws;
    const int B = in_sizes[0];

    const int threads = 256;
    const int blocks  = (B + 3) / 4;   // one full wave per batch element

    sgns_partial_kernel<<<blocks, threads, 0, stream>>>(target, context, neg,
                                                        emb, partials, B);
    sgns_reduce_kernel<<<1, threads, 0, stream>>>(partials, out, blocks,
                                                  1.0f / (float)B);
}